// Round 1
// baseline (714.097 us; speedup 1.0000x reference)
//
#include <hip/hip_runtime.h>

// Problem constants (from reference): N=2048, L=4096, M=512, P=512
#define NN 2048
#define LL 4096
#define MM 512
#define PP 512

__device__ __forceinline__ float wave_reduce_sum(float v) {
#pragma unroll
    for (int off = 32; off > 0; off >>= 1)
        v += __shfl_xor(v, off, 64);
    return v;
}

__global__ __launch_bounds__(64) void clear_flags(int* flags, int n) {
    int i = threadIdx.x;
    if (i < n) flags[i] = 0;
}

// out[row] = dot(M1[row,:n1], v1) + (M2 ? dot(M2[row,:n2], v2) : 0) + scale*bias[row]
// scale = t_ptr ? 0.95^t : 1.0
__global__ __launch_bounds__(256) void rowdot2(
        const float* __restrict__ M1, const float* __restrict__ v1, int n1,
        const float* __restrict__ M2, const float* __restrict__ v2, int n2,
        const float* __restrict__ bias, const int* __restrict__ t_ptr,
        float* __restrict__ out, int rows) {
    int wid  = (int)((blockIdx.x * 256u + threadIdx.x) >> 6);
    int lane = threadIdx.x & 63;
    if (wid >= rows) return;
    float acc = 0.0f;
    {
        const float4* Mr = reinterpret_cast<const float4*>(M1 + (size_t)wid * n1);
        const float4* V  = reinterpret_cast<const float4*>(v1);
        int nv = n1 >> 2;
        for (int c = lane; c < nv; c += 64) {
            float4 m = Mr[c], vv = V[c];
            acc = fmaf(m.x, vv.x, acc);
            acc = fmaf(m.y, vv.y, acc);
            acc = fmaf(m.z, vv.z, acc);
            acc = fmaf(m.w, vv.w, acc);
        }
    }
    if (M2) {
        const float4* Mr = reinterpret_cast<const float4*>(M2 + (size_t)wid * n2);
        const float4* V  = reinterpret_cast<const float4*>(v2);
        int nv = n2 >> 2;
        for (int c = lane; c < nv; c += 64) {
            float4 m = Mr[c], vv = V[c];
            acc = fmaf(m.x, vv.x, acc);
            acc = fmaf(m.y, vv.y, acc);
            acc = fmaf(m.z, vv.z, acc);
            acc = fmaf(m.w, vv.w, acc);
        }
    }
    acc = wave_reduce_sum(acc);
    if (lane == 0) {
        float scale = 1.0f;
        if (t_ptr) scale = __powf(0.95f, (float)(*t_ptr));
        out[wid] = fmaf(scale, bias[wid], acc);
    }
}

// Pipelined exact block forward-substitution with tanh:
// eps[i] = tanh((a[i] + D11[i,:i]·eps[:i]) / Lambda[i])
// 64 WGs, WG k owns rows [64k, 64k+64). Device-scope flag handoff.
__global__ __launch_bounds__(256) void trsv_tanh(
        const float* __restrict__ D11, const float* __restrict__ a,
        const float* __restrict__ Lambda, float* __restrict__ eps_g,
        int* __restrict__ flags) {
    const int k    = blockIdx.x;
    const int base = k * 64;
    const int tid  = threadIdx.x;
    const int lane = tid & 63;
    const int w    = tid >> 6;

    __shared__ float diag[64 * 64];   // diag[c*64 + r] = D11[base+r][base+c]
    __shared__ float s_arr[64];

    // Preload diagonal block (transposed for column access). Static data: load early.
    for (int idx = tid; idx < 64 * 64; idx += 256) {
        int r = idx >> 6, c = idx & 63;
        diag[c * 64 + r] = D11[(size_t)(base + r) * LL + base + c];
    }

    // Cross-block accumulation: wave w handles rows base + w*16 + rr
    float p[16];
#pragma unroll
    for (int rr = 0; rr < 16; ++rr) p[rr] = 0.0f;

    for (int j = 0; j < k; ++j) {
        if (tid == 0) {
            while (__hip_atomic_load(&flags[j], __ATOMIC_ACQUIRE,
                                     __HIP_MEMORY_SCOPE_AGENT) == 0)
                __builtin_amdgcn_s_sleep(1);
        }
        __syncthreads();
        float e = __hip_atomic_load(&eps_g[j * 64 + lane], __ATOMIC_RELAXED,
                                    __HIP_MEMORY_SCOPE_AGENT);
        const float* Dbase = D11 + (size_t)(base + w * 16) * LL + j * 64 + lane;
#pragma unroll
        for (int rr = 0; rr < 16; ++rr)
            p[rr] = fmaf(Dbase[(size_t)rr * LL], e, p[rr]);
    }

#pragma unroll
    for (int rr = 0; rr < 16; ++rr) {
        float s = wave_reduce_sum(p[rr]);
        if (lane == 0) s_arr[w * 16 + rr] = s;
    }
    __syncthreads();

    if (w == 0) {
        const int row = base + lane;
        float s  = a[row] + s_arr[lane];
        float kk = 2.885390082f / Lambda[row];  // 2*log2(e)/Lambda
        float eown = 0.0f;
        // tanh(t) = 1 - 2/(exp2(2t*log2e) + 1), t = s/Lambda
        for (int c = 0; c < 64; ++c) {
            float cand = 1.0f - 2.0f * __builtin_amdgcn_rcpf(exp2f(s * kk) + 1.0f);
            float ec = __shfl(cand, c, 64);
            if (lane == c) eown = ec;
            // diag[c][lane] == 0 for lane <= c (strictly lower), so safe unpredicated
            s = fmaf(diag[c * 64 + lane], ec, s);
        }
        __hip_atomic_store(&eps_g[base + lane], eown, __ATOMIC_RELAXED,
                           __HIP_MEMORY_SCOPE_AGENT);
        __threadfence();
        if (lane == 0)
            __hip_atomic_store(&flags[k], 1, __ATOMIC_RELEASE,
                               __HIP_MEMORY_SCOPE_AGENT);
    }
}

// One Richardson iteration: xout[i] = xin[i] + b[i] - dot(E[i,:], xin)
__global__ __launch_bounds__(256) void rich_iter(
        const float* __restrict__ E, const float* __restrict__ xin,
        const float* __restrict__ b, float* __restrict__ xout, int n) {
    int wid  = (int)((blockIdx.x * 256u + threadIdx.x) >> 6);
    int lane = threadIdx.x & 63;
    if (wid >= n) return;
    const float4* Er = reinterpret_cast<const float4*>(E + (size_t)wid * n);
    const float4* X  = reinterpret_cast<const float4*>(xin);
    float acc = 0.0f;
    int nv = n >> 2;
    for (int c = lane; c < nv; c += 64) {
        float4 m = Er[c], vv = X[c];
        acc = fmaf(m.x, vv.x, acc);
        acc = fmaf(m.y, vv.y, acc);
        acc = fmaf(m.z, vv.z, acc);
        acc = fmaf(m.w, vv.w, acc);
    }
    acc = wave_reduce_sum(acc);
    if (lane == 0) xout[wid] = xin[wid] + b[wid] - acc;
}

extern "C" void kernel_launch(void* const* d_in, const int* in_sizes, int n_in,
                              void* d_out, int out_size, void* d_ws, size_t ws_size,
                              hipStream_t stream) {
    const float* x   = (const float*)d_in[0];
    const float* u   = (const float*)d_in[1];
    const float* C1  = (const float*)d_in[2];
    const float* D11 = (const float*)d_in[3];
    const float* D12 = (const float*)d_in[4];
    const float* Lam = (const float*)d_in[5];
    const float* F   = (const float*)d_in[6];
    const float* B1  = (const float*)d_in[7];
    const float* B2  = (const float*)d_in[8];
    const float* E   = (const float*)d_in[9];
    const float* C2  = (const float*)d_in[10];
    const float* D21 = (const float*)d_in[11];
    const float* D22 = (const float*)d_in[12];
    const float* bv  = (const float*)d_in[13];
    const float* bx  = (const float*)d_in[14];
    const float* bu  = (const float*)d_in[15];
    const int*   t   = (const int*)d_in[16];

    float* ws   = (float*)d_ws;
    float* a    = ws;             // L
    float* eps  = ws + 4096;      // L
    float* q    = ws + 8192;      // N
    float* b    = ws + 10240;     // N
    float* y0   = ws + 12288;     // P
    float* xa   = ws + 12800;     // N
    float* xb   = ws + 14848;     // N
    int*   flags = (int*)(ws + 16896);  // 64 ints

    float* yout = (float*)d_out;         // P
    float* xout = (float*)d_out + PP;    // N

    clear_flags<<<1, 64, 0, stream>>>(flags, 64);

    dim3 blk(256);
    // a = C1 x + D12 u + decay*bv
    rowdot2<<<LL / 4, blk, 0, stream>>>(C1, x, NN, D12, u, MM, bv, t, a, LL);
    // q = F x + B2 u + decay*bx
    rowdot2<<<NN / 4, blk, 0, stream>>>(F, x, NN, B2, u, MM, bx, t, q, NN);
    // y0 = C2 x + D22 u + decay*bu
    rowdot2<<<PP / 4, blk, 0, stream>>>(C2, x, NN, D22, u, MM, bu, t, y0, PP);
    // eps (exact triangular tanh solve)
    trsv_tanh<<<64, 256, 0, stream>>>(D11, a, Lam, eps, flags);
    // y = D21 eps + y0  -> d_out[0:P)
    rowdot2<<<PP / 4, blk, 0, stream>>>(D21, eps, LL, nullptr, nullptr, 0, y0, nullptr, yout, PP);
    // b = B1 eps + q   (this is E_x_)
    rowdot2<<<NN / 4, blk, 0, stream>>>(B1, eps, LL, nullptr, nullptr, 0, q, nullptr, b, NN);

    // Solve E x_ = b by Richardson iteration (rho(I-E) ~ 0.45)
    const float* xin = b;
    for (int i = 0; i < 16; ++i) {
        float* xo = (i == 15) ? xout : ((i & 1) ? xb : xa);
        rich_iter<<<NN / 4, blk, 0, stream>>>(E, xin, b, xo, NN);
        xin = xo;
    }
}

// Round 2
// 182.200 us; speedup vs baseline: 3.9193x; 3.9193x over previous
//
#include <hip/hip_runtime.h>

// Problem constants (from reference): N=2048, L=4096, M=512, P=512
#define NN 2048
#define LL 4096
#define MM 512
#define PP 512

#define JACOBI_EXTRA 13   // total tanh-Jacobi applications = 1 (init) + 13
#define RICH_ITERS 10

__device__ __forceinline__ float wave_reduce_sum(float v) {
#pragma unroll
    for (int off = 32; off > 0; off >>= 1)
        v += __shfl_xor(v, off, 64);
    return v;
}

// out[row] = dot(M1[row,:n1], v1) + (M2 ? dot(M2[row,:n2], v2) : 0) + scale*bias[row]
// scale = t_ptr ? 0.95^t : 1.0.  If Lam != nullptr, also writes eps0[row] = tanh(out[row]/Lam[row]).
__global__ __launch_bounds__(256) void rowdot2(
        const float* __restrict__ M1, const float* __restrict__ v1, int n1,
        const float* __restrict__ M2, const float* __restrict__ v2, int n2,
        const float* __restrict__ bias, const int* __restrict__ t_ptr,
        float* __restrict__ out, int rows,
        const float* __restrict__ Lam, float* __restrict__ eps0) {
    int wid  = (int)((blockIdx.x * 256u + threadIdx.x) >> 6);
    int lane = threadIdx.x & 63;
    if (wid >= rows) return;
    float acc = 0.0f;
    {
        const float4* Mr = reinterpret_cast<const float4*>(M1 + (size_t)wid * n1);
        const float4* V  = reinterpret_cast<const float4*>(v1);
        int nv = n1 >> 2;
        for (int c = lane; c < nv; c += 64) {
            float4 m = Mr[c], vv = V[c];
            acc = fmaf(m.x, vv.x, acc);
            acc = fmaf(m.y, vv.y, acc);
            acc = fmaf(m.z, vv.z, acc);
            acc = fmaf(m.w, vv.w, acc);
        }
    }
    if (M2) {
        const float4* Mr = reinterpret_cast<const float4*>(M2 + (size_t)wid * n2);
        const float4* V  = reinterpret_cast<const float4*>(v2);
        int nv = n2 >> 2;
        for (int c = lane; c < nv; c += 64) {
            float4 m = Mr[c], vv = V[c];
            acc = fmaf(m.x, vv.x, acc);
            acc = fmaf(m.y, vv.y, acc);
            acc = fmaf(m.z, vv.z, acc);
            acc = fmaf(m.w, vv.w, acc);
        }
    }
    acc = wave_reduce_sum(acc);
    if (lane == 0) {
        float scale = 1.0f;
        if (t_ptr) scale = __powf(0.95f, (float)(*t_ptr));
        float r = fmaf(scale, bias[wid], acc);
        out[wid] = r;
        if (Lam) eps0[wid] = tanhf(r / Lam[wid]);
    }
}

// One nonlinear Jacobi sweep over the strictly-lower-triangular system:
// eps_out[i] = tanh((a[i] + D11[i,0:i] . eps_in[0:i]) / Lambda[i])
// One wave per row; rows permuted by odd multiplier for load balance.
// Reading D11[i][j] for j >= i is safe: entries are exactly 0 (strict tril),
// so rounding the row length up to a float4 boundary contributes nothing.
__global__ __launch_bounds__(256) void jacobi_iter(
        const float* __restrict__ D11, const float* __restrict__ a,
        const float* __restrict__ Lam,
        const float* __restrict__ eps_in, float* __restrict__ eps_out) {
    int wg   = (int)((blockIdx.x * 256u + threadIdx.x) >> 6);
    int lane = threadIdx.x & 63;
    int row  = (wg * 2731) & (LL - 1);   // odd multiplier -> bijection mod 4096
    int nf4  = (row + 3) >> 2;           // float4 count covering cols [0, row)
    const float4* Dr = reinterpret_cast<const float4*>(D11 + (size_t)row * LL);
    const float4* Ev = reinterpret_cast<const float4*>(eps_in);
    float acc = 0.0f;
    for (int c = lane; c < nf4; c += 64) {
        float4 m = Dr[c], vv = Ev[c];
        acc = fmaf(m.x, vv.x, acc);
        acc = fmaf(m.y, vv.y, acc);
        acc = fmaf(m.z, vv.z, acc);
        acc = fmaf(m.w, vv.w, acc);
    }
    acc = wave_reduce_sum(acc);
    if (lane == 0)
        eps_out[row] = tanhf((a[row] + acc) / Lam[row]);
}

// One Richardson iteration: xout[i] = xin[i] + b[i] - dot(E[i,:], xin)
__global__ __launch_bounds__(256) void rich_iter(
        const float* __restrict__ E, const float* __restrict__ xin,
        const float* __restrict__ b, float* __restrict__ xout, int n) {
    int wid  = (int)((blockIdx.x * 256u + threadIdx.x) >> 6);
    int lane = threadIdx.x & 63;
    if (wid >= n) return;
    const float4* Er = reinterpret_cast<const float4*>(E + (size_t)wid * n);
    const float4* X  = reinterpret_cast<const float4*>(xin);
    float acc = 0.0f;
    int nv = n >> 2;
    for (int c = lane; c < nv; c += 64) {
        float4 m = Er[c], vv = X[c];
        acc = fmaf(m.x, vv.x, acc);
        acc = fmaf(m.y, vv.y, acc);
        acc = fmaf(m.z, vv.z, acc);
        acc = fmaf(m.w, vv.w, acc);
    }
    acc = wave_reduce_sum(acc);
    if (lane == 0) xout[wid] = xin[wid] + b[wid] - acc;
}

extern "C" void kernel_launch(void* const* d_in, const int* in_sizes, int n_in,
                              void* d_out, int out_size, void* d_ws, size_t ws_size,
                              hipStream_t stream) {
    const float* x   = (const float*)d_in[0];
    const float* u   = (const float*)d_in[1];
    const float* C1  = (const float*)d_in[2];
    const float* D11 = (const float*)d_in[3];
    const float* D12 = (const float*)d_in[4];
    const float* Lam = (const float*)d_in[5];
    const float* F   = (const float*)d_in[6];
    const float* B1  = (const float*)d_in[7];
    const float* B2  = (const float*)d_in[8];
    const float* E   = (const float*)d_in[9];
    const float* C2  = (const float*)d_in[10];
    const float* D21 = (const float*)d_in[11];
    const float* D22 = (const float*)d_in[12];
    const float* bv  = (const float*)d_in[13];
    const float* bx  = (const float*)d_in[14];
    const float* bu  = (const float*)d_in[15];
    const int*   t   = (const int*)d_in[16];

    float* ws   = (float*)d_ws;
    float* a    = ws;              // L
    float* epsA = ws + 4096;       // L
    float* epsB = ws + 8192;       // L
    float* q    = ws + 12288;      // N
    float* b    = ws + 14336;      // N
    float* y0   = ws + 16384;      // P
    float* xa   = ws + 16896;      // N
    float* xb   = ws + 18944;      // N

    float* yout = (float*)d_out;         // P
    float* xout = (float*)d_out + PP;    // N

    dim3 blk(256);
    // a = C1 x + D12 u + decay*bv; epsA = tanh(a/Lambda) (Jacobi step 1)
    rowdot2<<<LL / 4, blk, 0, stream>>>(C1, x, NN, D12, u, MM, bv, t, a, LL, Lam, epsA);
    // q = F x + B2 u + decay*bx
    rowdot2<<<NN / 4, blk, 0, stream>>>(F, x, NN, B2, u, MM, bx, t, q, NN, nullptr, nullptr);
    // y0 = C2 x + D22 u + decay*bu
    rowdot2<<<PP / 4, blk, 0, stream>>>(C2, x, NN, D22, u, MM, bu, t, y0, PP, nullptr, nullptr);

    // Nonlinear Jacobi sweeps for the strictly-lower-triangular tanh system
    const float* ein = epsA;
    float* eout = epsB;
    for (int i = 0; i < JACOBI_EXTRA; ++i) {
        jacobi_iter<<<LL / 4, blk, 0, stream>>>(D11, a, Lam, ein, eout);
        const float* tmp = eout; eout = (float*)ein; ein = tmp;
    }
    const float* eps = ein;

    // y = D21 eps + y0  -> d_out[0:P)
    rowdot2<<<PP / 4, blk, 0, stream>>>(D21, eps, LL, nullptr, nullptr, 0, y0, nullptr, yout, PP, nullptr, nullptr);
    // b = B1 eps + q   (this is E_x_)
    rowdot2<<<NN / 4, blk, 0, stream>>>(B1, eps, LL, nullptr, nullptr, 0, q, nullptr, b, NN, nullptr, nullptr);

    // Solve E x_ = b by Richardson iteration (rho(I-E) ~ 0.45)
    const float* xin = b;
    for (int i = 0; i < RICH_ITERS; ++i) {
        float* xo = (i == RICH_ITERS - 1) ? xout : ((i & 1) ? xb : xa);
        rich_iter<<<NN / 4, blk, 0, stream>>>(E, xin, b, xo, NN);
        xin = xo;
    }
}

// Round 3
// 181.866 us; speedup vs baseline: 3.9265x; 1.0018x over previous
//
#include <hip/hip_runtime.h>

// Problem constants (from reference): N=2048, L=4096, M=512, P=512
#define NN 2048
#define LL 4096
#define MM 512
#define PP 512

#define JACOBI_EXTRA 13   // total tanh-Jacobi applications = 1 (init) + 13
#define RICH_ITERS 10

__device__ __forceinline__ float wave_reduce_sum(float v) {
#pragma unroll
    for (int off = 32; off > 0; off >>= 1)
        v += __shfl_xor(v, off, 64);
    return v;
}

// out[row] = dot(M1[row,:n1], v1) + (M2 ? dot(M2[row,:n2], v2) : 0) + scale*bias[row]
// scale = t_ptr ? 0.95^t : 1.0.  If Lam != nullptr, also writes eps0[row] = tanh(out[row]/Lam[row]).
__global__ __launch_bounds__(256) void rowdot2(
        const float* __restrict__ M1, const float* __restrict__ v1, int n1,
        const float* __restrict__ M2, const float* __restrict__ v2, int n2,
        const float* __restrict__ bias, const int* __restrict__ t_ptr,
        float* __restrict__ out, int rows,
        const float* __restrict__ Lam, float* __restrict__ eps0) {
    int wid  = (int)((blockIdx.x * 256u + threadIdx.x) >> 6);
    int lane = threadIdx.x & 63;
    if (wid >= rows) return;
    float acc = 0.0f;
    {
        const float4* Mr = reinterpret_cast<const float4*>(M1 + (size_t)wid * n1);
        const float4* V  = reinterpret_cast<const float4*>(v1);
        int nv = n1 >> 2;
        for (int c = lane; c < nv; c += 64) {
            float4 m = Mr[c], vv = V[c];
            acc = fmaf(m.x, vv.x, acc);
            acc = fmaf(m.y, vv.y, acc);
            acc = fmaf(m.z, vv.z, acc);
            acc = fmaf(m.w, vv.w, acc);
        }
    }
    if (M2) {
        const float4* Mr = reinterpret_cast<const float4*>(M2 + (size_t)wid * n2);
        const float4* V  = reinterpret_cast<const float4*>(v2);
        int nv = n2 >> 2;
        for (int c = lane; c < nv; c += 64) {
            float4 m = Mr[c], vv = V[c];
            acc = fmaf(m.x, vv.x, acc);
            acc = fmaf(m.y, vv.y, acc);
            acc = fmaf(m.z, vv.z, acc);
            acc = fmaf(m.w, vv.w, acc);
        }
    }
    acc = wave_reduce_sum(acc);
    if (lane == 0) {
        float scale = 1.0f;
        if (t_ptr) scale = __powf(0.95f, (float)(*t_ptr));
        float r = fmaf(scale, bias[wid], acc);
        out[wid] = r;
        if (Lam) eps0[wid] = tanhf(r / Lam[wid]);
    }
}

// One nonlinear Jacobi sweep over the strictly-lower-triangular system:
// eps_out[i] = tanh((a[i] + D11[i,0:i] . eps_in[0:i]) / Lambda[i])
// One wave per row; rows permuted by odd multiplier for load balance.
// Reading D11[i][j] for j >= i is safe: entries are exactly 0 (strict tril),
// so rounding the row length up to a float4 boundary contributes nothing.
__global__ __launch_bounds__(256) void jacobi_iter(
        const float* __restrict__ D11, const float* __restrict__ a,
        const float* __restrict__ Lam,
        const float* __restrict__ eps_in, float* __restrict__ eps_out) {
    int wg   = (int)((blockIdx.x * 256u + threadIdx.x) >> 6);
    int lane = threadIdx.x & 63;
    int row  = (wg * 2731) & (LL - 1);   // odd multiplier -> bijection mod 4096
    int nf4  = (row + 3) >> 2;           // float4 count covering cols [0, row)
    const float4* Dr = reinterpret_cast<const float4*>(D11 + (size_t)row * LL);
    const float4* Ev = reinterpret_cast<const float4*>(eps_in);
    float acc = 0.0f;
    for (int c = lane; c < nf4; c += 64) {
        float4 m = Dr[c], vv = Ev[c];
        acc = fmaf(m.x, vv.x, acc);
        acc = fmaf(m.y, vv.y, acc);
        acc = fmaf(m.z, vv.z, acc);
        acc = fmaf(m.w, vv.w, acc);
    }
    acc = wave_reduce_sum(acc);
    if (lane == 0)
        eps_out[row] = tanhf((a[row] + acc) / Lam[row]);
}

// One Richardson iteration: xout[i] = xin[i] + b[i] - dot(E[i,:], xin)
__global__ __launch_bounds__(256) void rich_iter(
        const float* __restrict__ E, const float* __restrict__ xin,
        const float* __restrict__ b, float* __restrict__ xout, int n) {
    int wid  = (int)((blockIdx.x * 256u + threadIdx.x) >> 6);
    int lane = threadIdx.x & 63;
    if (wid >= n) return;
    const float4* Er = reinterpret_cast<const float4*>(E + (size_t)wid * n);
    const float4* X  = reinterpret_cast<const float4*>(xin);
    float acc = 0.0f;
    int nv = n >> 2;
    for (int c = lane; c < nv; c += 64) {
        float4 m = Er[c], vv = X[c];
        acc = fmaf(m.x, vv.x, acc);
        acc = fmaf(m.y, vv.y, acc);
        acc = fmaf(m.z, vv.z, acc);
        acc = fmaf(m.w, vv.w, acc);
    }
    acc = wave_reduce_sum(acc);
    if (lane == 0) xout[wid] = xin[wid] + b[wid] - acc;
}

extern "C" void kernel_launch(void* const* d_in, const int* in_sizes, int n_in,
                              void* d_out, int out_size, void* d_ws, size_t ws_size,
                              hipStream_t stream) {
    const float* x   = (const float*)d_in[0];
    const float* u   = (const float*)d_in[1];
    const float* C1  = (const float*)d_in[2];
    const float* D11 = (const float*)d_in[3];
    const float* D12 = (const float*)d_in[4];
    const float* Lam = (const float*)d_in[5];
    const float* F   = (const float*)d_in[6];
    const float* B1  = (const float*)d_in[7];
    const float* B2  = (const float*)d_in[8];
    const float* E   = (const float*)d_in[9];
    const float* C2  = (const float*)d_in[10];
    const float* D21 = (const float*)d_in[11];
    const float* D22 = (const float*)d_in[12];
    const float* bv  = (const float*)d_in[13];
    const float* bx  = (const float*)d_in[14];
    const float* bu  = (const float*)d_in[15];
    const int*   t   = (const int*)d_in[16];

    float* ws   = (float*)d_ws;
    float* a    = ws;              // L
    float* epsA = ws + 4096;       // L
    float* epsB = ws + 8192;       // L
    float* q    = ws + 12288;      // N
    float* b    = ws + 14336;      // N
    float* y0   = ws + 16384;      // P
    float* xa   = ws + 16896;      // N
    float* xb   = ws + 18944;      // N

    float* yout = (float*)d_out;         // P
    float* xout = (float*)d_out + PP;    // N

    dim3 blk(256);
    // a = C1 x + D12 u + decay*bv; epsA = tanh(a/Lambda) (Jacobi step 1)
    rowdot2<<<LL / 4, blk, 0, stream>>>(C1, x, NN, D12, u, MM, bv, t, a, LL, Lam, epsA);
    // q = F x + B2 u + decay*bx
    rowdot2<<<NN / 4, blk, 0, stream>>>(F, x, NN, B2, u, MM, bx, t, q, NN, nullptr, nullptr);
    // y0 = C2 x + D22 u + decay*bu
    rowdot2<<<PP / 4, blk, 0, stream>>>(C2, x, NN, D22, u, MM, bu, t, y0, PP, nullptr, nullptr);

    // Nonlinear Jacobi sweeps for the strictly-lower-triangular tanh system
    const float* ein = epsA;
    float* eout = epsB;
    for (int i = 0; i < JACOBI_EXTRA; ++i) {
        jacobi_iter<<<LL / 4, blk, 0, stream>>>(D11, a, Lam, ein, eout);
        const float* tmp = eout; eout = (float*)ein; ein = tmp;
    }
    const float* eps = ein;

    // y = D21 eps + y0  -> d_out[0:P)
    rowdot2<<<PP / 4, blk, 0, stream>>>(D21, eps, LL, nullptr, nullptr, 0, y0, nullptr, yout, PP, nullptr, nullptr);
    // b = B1 eps + q   (this is E_x_)
    rowdot2<<<NN / 4, blk, 0, stream>>>(B1, eps, LL, nullptr, nullptr, 0, q, nullptr, b, NN, nullptr, nullptr);

    // Solve E x_ = b by Richardson iteration (rho(I-E) ~ 0.45)
    const float* xin = b;
    for (int i = 0; i < RICH_ITERS; ++i) {
        float* xo = (i == RICH_ITERS - 1) ? xout : ((i & 1) ? xb : xa);
        rich_iter<<<NN / 4, blk, 0, stream>>>(E, xin, b, xo, NN);
        xin = xo;
    }
}

// Round 4
// 181.844 us; speedup vs baseline: 3.9270x; 1.0001x over previous
//
#include <hip/hip_runtime.h>

// Problem constants (from reference): N=2048, L=4096, M=512, P=512
#define NN 2048
#define LL 4096
#define MM 512
#define PP 512

#define JACOBI_EXTRA 13   // total tanh-Jacobi applications = 1 (init) + 13
#define RICH_ITERS 10

__device__ __forceinline__ float wave_reduce_sum(float v) {
#pragma unroll
    for (int off = 32; off > 0; off >>= 1)
        v += __shfl_xor(v, off, 64);
    return v;
}

// out[row] = dot(M1[row,:n1], v1) + (M2 ? dot(M2[row,:n2], v2) : 0) + scale*bias[row]
// scale = t_ptr ? 0.95^t : 1.0.  If Lam != nullptr, also writes eps0[row] = tanh(out[row]/Lam[row]).
__global__ __launch_bounds__(256) void rowdot2(
        const float* __restrict__ M1, const float* __restrict__ v1, int n1,
        const float* __restrict__ M2, const float* __restrict__ v2, int n2,
        const float* __restrict__ bias, const int* __restrict__ t_ptr,
        float* __restrict__ out, int rows,
        const float* __restrict__ Lam, float* __restrict__ eps0) {
    int wid  = (int)((blockIdx.x * 256u + threadIdx.x) >> 6);
    int lane = threadIdx.x & 63;
    if (wid >= rows) return;
    float acc = 0.0f;
    {
        const float4* Mr = reinterpret_cast<const float4*>(M1 + (size_t)wid * n1);
        const float4* V  = reinterpret_cast<const float4*>(v1);
        int nv = n1 >> 2;
        for (int c = lane; c < nv; c += 64) {
            float4 m = Mr[c], vv = V[c];
            acc = fmaf(m.x, vv.x, acc);
            acc = fmaf(m.y, vv.y, acc);
            acc = fmaf(m.z, vv.z, acc);
            acc = fmaf(m.w, vv.w, acc);
        }
    }
    if (M2) {
        const float4* Mr = reinterpret_cast<const float4*>(M2 + (size_t)wid * n2);
        const float4* V  = reinterpret_cast<const float4*>(v2);
        int nv = n2 >> 2;
        for (int c = lane; c < nv; c += 64) {
            float4 m = Mr[c], vv = V[c];
            acc = fmaf(m.x, vv.x, acc);
            acc = fmaf(m.y, vv.y, acc);
            acc = fmaf(m.z, vv.z, acc);
            acc = fmaf(m.w, vv.w, acc);
        }
    }
    acc = wave_reduce_sum(acc);
    if (lane == 0) {
        float scale = 1.0f;
        if (t_ptr) scale = __powf(0.95f, (float)(*t_ptr));
        float r = fmaf(scale, bias[wid], acc);
        out[wid] = r;
        if (Lam) eps0[wid] = tanhf(r / Lam[wid]);
    }
}

// One nonlinear Jacobi sweep over the strictly-lower-triangular system:
// eps_out[i] = tanh((a[i] + D11[i,0:i] . eps_in[0:i]) / Lambda[i])
// One wave per row; rows permuted by odd multiplier for load balance.
// Reading D11[i][j] for j >= i is safe: entries are exactly 0 (strict tril),
// so rounding the row length up to a float4 boundary contributes nothing.
__global__ __launch_bounds__(256) void jacobi_iter(
        const float* __restrict__ D11, const float* __restrict__ a,
        const float* __restrict__ Lam,
        const float* __restrict__ eps_in, float* __restrict__ eps_out) {
    int wg   = (int)((blockIdx.x * 256u + threadIdx.x) >> 6);
    int lane = threadIdx.x & 63;
    int row  = (wg * 2731) & (LL - 1);   // odd multiplier -> bijection mod 4096
    int nf4  = (row + 3) >> 2;           // float4 count covering cols [0, row)
    const float4* Dr = reinterpret_cast<const float4*>(D11 + (size_t)row * LL);
    const float4* Ev = reinterpret_cast<const float4*>(eps_in);
    float acc = 0.0f;
    for (int c = lane; c < nf4; c += 64) {
        float4 m = Dr[c], vv = Ev[c];
        acc = fmaf(m.x, vv.x, acc);
        acc = fmaf(m.y, vv.y, acc);
        acc = fmaf(m.z, vv.z, acc);
        acc = fmaf(m.w, vv.w, acc);
    }
    acc = wave_reduce_sum(acc);
    if (lane == 0)
        eps_out[row] = tanhf((a[row] + acc) / Lam[row]);
}

// One Richardson iteration: xout[i] = xin[i] + b[i] - dot(E[i,:], xin)
__global__ __launch_bounds__(256) void rich_iter(
        const float* __restrict__ E, const float* __restrict__ xin,
        const float* __restrict__ b, float* __restrict__ xout, int n) {
    int wid  = (int)((blockIdx.x * 256u + threadIdx.x) >> 6);
    int lane = threadIdx.x & 63;
    if (wid >= n) return;
    const float4* Er = reinterpret_cast<const float4*>(E + (size_t)wid * n);
    const float4* X  = reinterpret_cast<const float4*>(xin);
    float acc = 0.0f;
    int nv = n >> 2;
    for (int c = lane; c < nv; c += 64) {
        float4 m = Er[c], vv = X[c];
        acc = fmaf(m.x, vv.x, acc);
        acc = fmaf(m.y, vv.y, acc);
        acc = fmaf(m.z, vv.z, acc);
        acc = fmaf(m.w, vv.w, acc);
    }
    acc = wave_reduce_sum(acc);
    if (lane == 0) xout[wid] = xin[wid] + b[wid] - acc;
}

extern "C" void kernel_launch(void* const* d_in, const int* in_sizes, int n_in,
                              void* d_out, int out_size, void* d_ws, size_t ws_size,
                              hipStream_t stream) {
    const float* x   = (const float*)d_in[0];
    const float* u   = (const float*)d_in[1];
    const float* C1  = (const float*)d_in[2];
    const float* D11 = (const float*)d_in[3];
    const float* D12 = (const float*)d_in[4];
    const float* Lam = (const float*)d_in[5];
    const float* F   = (const float*)d_in[6];
    const float* B1  = (const float*)d_in[7];
    const float* B2  = (const float*)d_in[8];
    const float* E   = (const float*)d_in[9];
    const float* C2  = (const float*)d_in[10];
    const float* D21 = (const float*)d_in[11];
    const float* D22 = (const float*)d_in[12];
    const float* bv  = (const float*)d_in[13];
    const float* bx  = (const float*)d_in[14];
    const float* bu  = (const float*)d_in[15];
    const int*   t   = (const int*)d_in[16];

    float* ws   = (float*)d_ws;
    float* a    = ws;              // L
    float* epsA = ws + 4096;       // L
    float* epsB = ws + 8192;       // L
    float* q    = ws + 12288;      // N
    float* b    = ws + 14336;      // N
    float* y0   = ws + 16384;      // P
    float* xa   = ws + 16896;      // N
    float* xb   = ws + 18944;      // N

    float* yout = (float*)d_out;         // P
    float* xout = (float*)d_out + PP;    // N

    dim3 blk(256);
    // a = C1 x + D12 u + decay*bv; epsA = tanh(a/Lambda) (Jacobi step 1)
    rowdot2<<<LL / 4, blk, 0, stream>>>(C1, x, NN, D12, u, MM, bv, t, a, LL, Lam, epsA);
    // q = F x + B2 u + decay*bx
    rowdot2<<<NN / 4, blk, 0, stream>>>(F, x, NN, B2, u, MM, bx, t, q, NN, nullptr, nullptr);
    // y0 = C2 x + D22 u + decay*bu
    rowdot2<<<PP / 4, blk, 0, stream>>>(C2, x, NN, D22, u, MM, bu, t, y0, PP, nullptr, nullptr);

    // Nonlinear Jacobi sweeps for the strictly-lower-triangular tanh system
    const float* ein = epsA;
    float* eout = epsB;
    for (int i = 0; i < JACOBI_EXTRA; ++i) {
        jacobi_iter<<<LL / 4, blk, 0, stream>>>(D11, a, Lam, ein, eout);
        const float* tmp = eout; eout = (float*)ein; ein = tmp;
    }
    const float* eps = ein;

    // y = D21 eps + y0  -> d_out[0:P)
    rowdot2<<<PP / 4, blk, 0, stream>>>(D21, eps, LL, nullptr, nullptr, 0, y0, nullptr, yout, PP, nullptr, nullptr);
    // b = B1 eps + q   (this is E_x_)
    rowdot2<<<NN / 4, blk, 0, stream>>>(B1, eps, LL, nullptr, nullptr, 0, q, nullptr, b, NN, nullptr, nullptr);

    // Solve E x_ = b by Richardson iteration (rho(I-E) ~ 0.45)
    const float* xin = b;
    for (int i = 0; i < RICH_ITERS; ++i) {
        float* xo = (i == RICH_ITERS - 1) ? xout : ((i & 1) ? xb : xa);
        rich_iter<<<NN / 4, blk, 0, stream>>>(E, xin, b, xo, NN);
        xin = xo;
    }
}